// Round 13
// baseline (555.327 us; speedup 1.0000x reference)
//
#include <hip/hip_runtime.h>
#include <math.h>

#define N_NODES 50000
#define N_EDGES 1600000
#define DIM 64
#define HEADS 8
#define EDGE_DIM 32

#define NB 256      // destination buckets
#define NPB 196     // nodes per bucket (196*256 = 50176 >= 50000)
#define ACAP 8192   // per-bucket capacity (mean 6250, sd ~79)
#define QS 8        // node-octants per bucket
#define NQ 25       // nodes per octant (8*25 = 200 >= 196)
#define CAPQ 1280   // per-octant edge capacity (mean 781, sd ~28 -> 18 sigma)

#define PART_T 512
#define EPT 8
#define PART_E (PART_T * EPT)  // 4096 edges per partition block

typedef __fp16 h2 __attribute__((ext_vector_type(2)));

// ---- bf16 helpers ----
__device__ __forceinline__ unsigned int f2bf(float f) {
    union { float f; unsigned int u; } c; c.f = f;
    unsigned int u = c.u;
    return (u + 0x7FFFu + ((u >> 16) & 1u)) >> 16;
}
__device__ __forceinline__ float bf_lo(unsigned int u) { return __uint_as_float(u << 16); }
__device__ __forceinline__ float bf_hi(unsigned int u) { return __uint_as_float(u & 0xFFFF0000u); }

// ---------------- K_prep: pack MLP weights as half2 pairs ----------------
__global__ __launch_bounds__(1024) void pack_weights(
    const float* __restrict__ We1, const float* __restrict__ We2,
    h2* __restrict__ w1p, h2* __restrict__ w2p)
{
    const int t = threadIdx.x;
    if (t < 512) {
        const int c = t >> 4, kk = t & 15;
        w1p[t] = __builtin_amdgcn_cvt_pkrtz(We1[(2 * kk) * EDGE_DIM + c],
                                            We1[(2 * kk + 1) * EDGE_DIM + c]);
    } else if (t < 512 + 128) {
        const int u = t - 512;
        const int h = u >> 4, cc = u & 15;
        w2p[u] = __builtin_amdgcn_cvt_pkrtz(We2[(2 * cc) * HEADS + h],
                                            We2[(2 * cc + 1) * HEADS + h]);
    }
}

// ---------------- K_A: bucket partition (no MLP), LDS-staged records ----------------
__global__ __launch_bounds__(512) void partition(
    const int* __restrict__ ei, int* __restrict__ gcur, uint2* __restrict__ A_rec)
{
    __shared__ int cnt[NB];
    __shared__ int base[NB];
    __shared__ int lbase[NB];
    __shared__ int total_s;
    __shared__ uint2 srec[PART_E];          // 32 KB
    __shared__ unsigned char sbkt[PART_E];  // 4 KB
    const int tid = threadIdx.x;
    if (tid < NB) cnt[tid] = 0;
    __syncthreads();
    const int e0 = blockIdx.x * PART_E;
    #pragma unroll
    for (int k = 0; k < EPT; ++k) {
        const int e = e0 + k * PART_T + tid;
        if (e < N_EDGES) atomicAdd(&cnt[ei[N_EDGES + e] / NPB], 1);
    }
    __syncthreads();
    if (tid < NB) lbase[tid] = cnt[tid];
    __syncthreads();
    for (int o = 1; o < NB; o <<= 1) {
        int t = 0;
        if (tid < NB && tid >= o) t = lbase[tid - o];
        __syncthreads();
        if (tid < NB) lbase[tid] += t;
        __syncthreads();
    }
    if (tid < NB) {
        const int inc = lbase[tid];
        const int c = cnt[tid];
        base[tid] = (c > 0) ? atomicAdd(&gcur[tid], c) : 0;
        lbase[tid] = inc - c;
        if (tid == NB - 1) total_s = inc;
        cnt[tid] = 0;
    }
    __syncthreads();
    #pragma unroll
    for (int k = 0; k < EPT; ++k) {
        const int e = e0 + k * PART_T + tid;
        if (e < N_EDGES) {
            const int i = ei[e];
            const int j = ei[N_EDGES + e];
            const int b = j / NPB;
            const int jl = j - b * NPB;
            const int s = lbase[b] + atomicAdd(&cnt[b], 1);
            srec[s] = make_uint2((unsigned)e, ((unsigned)jl << 24) | (unsigned)i);
            sbkt[s] = (unsigned char)b;
        }
    }
    __syncthreads();
    const int total = total_s;
    for (int s = tid; s < total; s += PART_T) {
        const int b = sbkt[s];
        const int gp = base[b] + (s - lbase[b]);
        if (gp < ACAP) A_rec[(size_t)b * ACAP + gp] = srec[s];
    }
}

// ---------------- K1: Q/K/V projections; K,V packed bf16 into one uint row ----------------
__global__ __launch_bounds__(256) void qkv_proj(
    const float* __restrict__ x,
    const float* __restrict__ WQ, const float* __restrict__ bQ,
    const float* __restrict__ WK, const float* __restrict__ bK,
    const float* __restrict__ WV, const float* __restrict__ bV,
    float* __restrict__ Q, unsigned int* __restrict__ KV)
{
    __shared__ float sWQ[DIM * DIM];
    __shared__ float sWK[DIM * DIM];
    __shared__ float sWV[DIM * DIM];
    for (int t = threadIdx.x; t < DIM * DIM; t += blockDim.x) {
        sWQ[t] = WQ[t]; sWK[t] = WK[t]; sWV[t] = WV[t];
    }
    __syncthreads();
    const int lane = threadIdx.x & 63;
    const int wave = threadIdx.x >> 6;
    const int n = blockIdx.x * 4 + wave;
    if (n >= N_NODES) return;
    float xl = x[(size_t)n * DIM + lane];
    float aq = bQ[lane], ak = bK[lane], av = bV[lane];
    #pragma unroll
    for (int k = 0; k < DIM; ++k) {
        float xv = __shfl(xl, k, 64);
        aq += xv * sWQ[k * DIM + lane];
        ak += xv * sWK[k * DIM + lane];
        av += xv * sWV[k * DIM + lane];
    }
    Q[(size_t)n * DIM + lane] = aq;
    KV[(size_t)n * DIM + lane] = f2bf(ak) | (f2bf(av) << 16);  // K lo, V hi
}

// ---------------- K2: fused CSR-in-LDS + edge MLP + attention + out-proj ----------------
// One block per (bucket, node-octant). Build octant CSR in LDS; phase A runs the
// edge MLP one-edge-per-LANE (weights wave-uniform -> scalar pipe) into LDS bias;
// phase B is the proven per-node gather loop reading src/bias from LDS.
__global__ __launch_bounds__(256) void attn_fused(
    const int* __restrict__ gcur, const uint2* __restrict__ A_rec,
    const float* __restrict__ edge_attr,
    const h2* __restrict__ w1p, const float* __restrict__ be1,
    const h2* __restrict__ w2p, const float* __restrict__ be2,
    const float* __restrict__ Q, const unsigned int* __restrict__ KV,
    const float* __restrict__ WO, const float* __restrict__ bO,
    float* __restrict__ out)
{
    __shared__ unsigned int lds_e[CAPQ];     // 5 KB
    __shared__ unsigned short lds_i[CAPQ];   // 2.5 KB
    __shared__ uint4 sbias[CAPQ];            // 20 KB
    __shared__ int loff[NQ + 1];
    __shared__ int lcur[NQ];
    __shared__ int ldeg[NQ];
    const int tid = threadIdx.x;
    const int bq = blockIdx.x;
    const int b = bq >> 3;
    const int q = bq & 7;
    const int jl0 = q * NQ;
    const int jl1 = (jl0 + NQ < NPB) ? jl0 + NQ : NPB;
    const int nqn = jl1 - jl0;   // 21..25
    const int nb = min(gcur[b], ACAP);
    if (tid < NQ) ldeg[tid] = 0;
    __syncthreads();
    // octant degree histogram over the bucket's records
    for (int r = tid; r < nb; r += 256) {
        const int jl = (int)(A_rec[(size_t)b * ACAP + r].y >> 24);
        if (jl >= jl0 && jl < jl1) atomicAdd(&ldeg[jl - jl0], 1);
    }
    __syncthreads();
    // single-wave shfl scan of NQ degrees
    if (tid < 64) {
        int v = (tid < nqn) ? ldeg[tid] : 0;
        #pragma unroll
        for (int o = 1; o < 32; o <<= 1) {
            int t = __shfl_up(v, o, 64);
            if (tid >= o) v += t;
        }
        if (tid == 0) loff[0] = 0;
        if (tid < nqn) { loff[tid + 1] = v; lcur[tid] = 0; }
    }
    __syncthreads();
    // place records into octant CSR slots
    for (int r = tid; r < nb; r += 256) {
        const uint2 rec = A_rec[(size_t)b * ACAP + r];
        const int jl = (int)(rec.y >> 24);
        if (jl >= jl0 && jl < jl1) {
            const int s = loff[jl - jl0] + atomicAdd(&lcur[jl - jl0], 1);
            if (s < CAPQ) {
                lds_e[s] = rec.x;
                lds_i[s] = (unsigned short)(rec.y & 0xFFFFFFu);
            }
        }
    }
    __syncthreads();
    const int tot = (loff[nqn] < CAPQ) ? loff[nqn] : CAPQ;
    // ---- phase A: edge MLP, one edge per lane, weights via scalar pipe ----
    for (int s = tid; s < tot; s += 256) {
        const int e = (int)lds_e[s];
        float a[EDGE_DIM];
        const float4* ar = (const float4*)(edge_attr + (size_t)e * EDGE_DIM);
        #pragma unroll
        for (int p = 0; p < EDGE_DIM / 4; ++p) {
            float4 v = ar[p];
            a[p * 4 + 0] = v.x; a[p * 4 + 1] = v.y;
            a[p * 4 + 2] = v.z; a[p * 4 + 3] = v.w;
        }
        h2 a2[EDGE_DIM / 2];
        #pragma unroll
        for (int kk = 0; kk < EDGE_DIM / 2; ++kk)
            a2[kk] = __builtin_amdgcn_cvt_pkrtz(a[2 * kk], a[2 * kk + 1]);
        float sil[EDGE_DIM];
        #pragma unroll 8
        for (int c = 0; c < EDGE_DIM; ++c) {
            float sv = be1[c];
            #pragma unroll
            for (int kk = 0; kk < EDGE_DIM / 2; ++kk)
                sv = __builtin_amdgcn_fdot2(a2[kk], w1p[c * 16 + kk], sv, false);
            sil[c] = __fdividef(sv, 1.0f + __expf(-sv));
        }
        h2 s2[EDGE_DIM / 2];
        #pragma unroll
        for (int cc = 0; cc < EDGE_DIM / 2; ++cc)
            s2[cc] = __builtin_amdgcn_cvt_pkrtz(sil[2 * cc], sil[2 * cc + 1]);
        float b0f = be2[0], b1f = be2[1], b2f = be2[2], b3f = be2[3];
        float b4f = be2[4], b5f = be2[5], b6f = be2[6], b7f = be2[7];
        #pragma unroll
        for (int cc = 0; cc < EDGE_DIM / 2; ++cc) {
            b0f = __builtin_amdgcn_fdot2(s2[cc], w2p[0 * 16 + cc], b0f, false);
            b1f = __builtin_amdgcn_fdot2(s2[cc], w2p[1 * 16 + cc], b1f, false);
            b2f = __builtin_amdgcn_fdot2(s2[cc], w2p[2 * 16 + cc], b2f, false);
            b3f = __builtin_amdgcn_fdot2(s2[cc], w2p[3 * 16 + cc], b3f, false);
            b4f = __builtin_amdgcn_fdot2(s2[cc], w2p[4 * 16 + cc], b4f, false);
            b5f = __builtin_amdgcn_fdot2(s2[cc], w2p[5 * 16 + cc], b5f, false);
            b6f = __builtin_amdgcn_fdot2(s2[cc], w2p[6 * 16 + cc], b6f, false);
            b7f = __builtin_amdgcn_fdot2(s2[cc], w2p[7 * 16 + cc], b7f, false);
        }
        uint4 br;
        br.x = f2bf(b0f) | (f2bf(b1f) << 16);
        br.y = f2bf(b2f) | (f2bf(b3f) << 16);
        br.z = f2bf(b4f) | (f2bf(b5f) << 16);
        br.w = f2bf(b6f) | (f2bf(b7f) << 16);
        sbias[s] = br;
    }
    __syncthreads();
    // ---- phase B: per-node gather, softmax-sum, fused out-projection ----
    const int lane = tid & 63;
    const int wave = tid >> 6;  // 0..3
    const int h = lane >> 3;
    const unsigned short* sb16 = (const unsigned short*)sbias;
    const float inv_sqrt_dk = 0.35355339059327373f;
    for (int n = wave; n < nqn; n += 4) {
        const int j = b * NPB + jl0 + n;
        if (j >= N_NODES) continue;
        const int beg = (loff[n] < tot) ? loff[n] : tot;
        const int end = (loff[n + 1] < tot) ? loff[n + 1] : tot;
        const float qv = Q[(size_t)j * DIM + lane];
        float num = 0.0f, den = 1e-12f;
        int t = beg;
        for (; t + 3 < end; t += 4) {
            const int i0 = lds_i[t + 0];
            const int i1 = lds_i[t + 1];
            const int i2 = lds_i[t + 2];
            const int i3 = lds_i[t + 3];
            const unsigned int u0 = KV[(size_t)i0 * DIM + lane];
            const unsigned int u1 = KV[(size_t)i1 * DIM + lane];
            const unsigned int u2 = KV[(size_t)i2 * DIM + lane];
            const unsigned int u3 = KV[(size_t)i3 * DIM + lane];
            const float b0 = bf_lo((unsigned int)sb16[(t + 0) * 8 + h]);
            const float b1 = bf_lo((unsigned int)sb16[(t + 1) * 8 + h]);
            const float b2 = bf_lo((unsigned int)sb16[(t + 2) * 8 + h]);
            const float b3 = bf_lo((unsigned int)sb16[(t + 3) * 8 + h]);
            float d0 = qv * bf_lo(u0);
            float d1 = qv * bf_lo(u1);
            float d2 = qv * bf_lo(u2);
            float d3 = qv * bf_lo(u3);
            d0 += __shfl_xor(d0, 1, 64); d1 += __shfl_xor(d1, 1, 64);
            d2 += __shfl_xor(d2, 1, 64); d3 += __shfl_xor(d3, 1, 64);
            d0 += __shfl_xor(d0, 2, 64); d1 += __shfl_xor(d1, 2, 64);
            d2 += __shfl_xor(d2, 2, 64); d3 += __shfl_xor(d3, 2, 64);
            d0 += __shfl_xor(d0, 4, 64); d1 += __shfl_xor(d1, 4, 64);
            d2 += __shfl_xor(d2, 4, 64); d3 += __shfl_xor(d3, 4, 64);
            const float e0 = __expf(d0 * inv_sqrt_dk + b0);
            const float e1 = __expf(d1 * inv_sqrt_dk + b1);
            const float e2 = __expf(d2 * inv_sqrt_dk + b2);
            const float e3 = __expf(d3 * inv_sqrt_dk + b3);
            num += e0 * bf_hi(u0) + e1 * bf_hi(u1) + e2 * bf_hi(u2) + e3 * bf_hi(u3);
            den += e0 + e1 + e2 + e3;
        }
        for (; t < end; ++t) {
            const int i0 = lds_i[t];
            const unsigned int u0 = KV[(size_t)i0 * DIM + lane];
            const float b0 = bf_lo((unsigned int)sb16[t * 8 + h]);
            float d0 = qv * bf_lo(u0);
            d0 += __shfl_xor(d0, 1, 64);
            d0 += __shfl_xor(d0, 2, 64);
            d0 += __shfl_xor(d0, 4, 64);
            const float e0 = __expf(d0 * inv_sqrt_dk + b0);
            num += e0 * bf_hi(u0);
            den += e0;
        }
        const float av = num / den;
        float acc = bO[lane];
        #pragma unroll
        for (int k = 0; k < DIM; ++k)
            acc += __shfl(av, k, 64) * WO[k * DIM + lane];
        out[(size_t)j * DIM + lane] = acc;
    }
}

extern "C" void kernel_launch(void* const* d_in, const int* in_sizes, int n_in,
                              void* d_out, int out_size, void* d_ws, size_t ws_size,
                              hipStream_t stream) {
    const float* x    = (const float*)d_in[0];
    const int*   ei   = (const int*)d_in[1];
    const float* ea   = (const float*)d_in[2];
    const float* WQ   = (const float*)d_in[3];
    const float* bQ   = (const float*)d_in[4];
    const float* WK   = (const float*)d_in[5];
    const float* bK   = (const float*)d_in[6];
    const float* WV   = (const float*)d_in[7];
    const float* bV   = (const float*)d_in[8];
    const float* WO   = (const float*)d_in[9];
    const float* bO   = (const float*)d_in[10];
    const float* We1  = (const float*)d_in[11];
    const float* be1  = (const float*)d_in[12];
    const float* We2  = (const float*)d_in[13];
    const float* be2  = (const float*)d_in[14];
    float* out = (float*)d_out;

    char* ws = (char*)d_ws;
    size_t off_b = 0;
    auto alloc = [&](size_t bytes) {
        void* p = ws + off_b;
        off_b += (bytes + 255) & ~(size_t)255;
        return p;
    };
    float*        Q     = (float*)alloc((size_t)N_NODES * DIM * sizeof(float));
    unsigned int* KV    = (unsigned int*)alloc((size_t)N_NODES * DIM * sizeof(unsigned int));
    uint2*        A_rec = (uint2*)alloc((size_t)NB * ACAP * sizeof(uint2));
    int*          gcur  = (int*)alloc((size_t)NB * sizeof(int));
    h2*           w1p   = (h2*)alloc(512 * sizeof(h2));
    h2*           w2p   = (h2*)alloc(128 * sizeof(h2));

    (void)hipMemsetAsync(gcur, 0, (size_t)NB * sizeof(int), stream);

    pack_weights<<<1, 1024, 0, stream>>>(We1, We2, w1p, w2p);
    partition<<<(N_EDGES + PART_E - 1) / PART_E, PART_T, 0, stream>>>(ei, gcur, A_rec);
    qkv_proj<<<(N_NODES + 3) / 4, 256, 0, stream>>>(x, WQ, bQ, WK, bK, WV, bV, Q, KV);
    attn_fused<<<NB * QS, 256, 0, stream>>>(gcur, A_rec, ea, w1p, be1, w2p, be2,
                                            Q, KV, WO, bO, out);
}

// Round 14
// 349.038 us; speedup vs baseline: 1.5910x; 1.5910x over previous
//
#include <hip/hip_runtime.h>
#include <math.h>

#define N_NODES 50000
#define N_EDGES 1600000
#define DIM 64
#define HEADS 8
#define EDGE_DIM 32

#define NB 256      // destination buckets
#define NPB 196     // nodes per bucket (196*256 = 50176 >= 50000)
#define ACAP 8192   // per-bucket capacity (mean 6250, sd ~79 -> 24 sigma)
#define PART_T 512
#define EPT 4
#define PART_E (PART_T * EPT)  // 2048 edges per partition block

typedef __fp16 h2 __attribute__((ext_vector_type(2)));

// ---- bf16 helpers (RNE round via bit trick; inputs are finite) ----
__device__ __forceinline__ unsigned int f2bf(float f) {
    union { float f; unsigned int u; } c; c.f = f;
    unsigned int u = c.u;
    return (u + 0x7FFFu + ((u >> 16) & 1u)) >> 16;
}
__device__ __forceinline__ float bf_lo(unsigned int u) { return __uint_as_float(u << 16); }
__device__ __forceinline__ float bf_hi(unsigned int u) { return __uint_as_float(u & 0xFFFF0000u); }

// ---------------- K_prep: pack MLP weights as half2 pairs ----------------
__global__ __launch_bounds__(1024) void pack_weights(
    const float* __restrict__ We1, const float* __restrict__ We2,
    h2* __restrict__ w1p, h2* __restrict__ w2p)
{
    const int t = threadIdx.x;
    if (t < 512) {
        const int c = t >> 4, kk = t & 15;
        w1p[t] = __builtin_amdgcn_cvt_pkrtz(We1[(2 * kk) * EDGE_DIM + c],
                                            We1[(2 * kk + 1) * EDGE_DIM + c]);
    } else if (t < 512 + 128) {
        const int u = t - 512;
        const int h = u >> 4, cc = u & 15;
        w2p[u] = __builtin_amdgcn_cvt_pkrtz(We2[(2 * cc) * HEADS + h],
                                            We2[(2 * cc + 1) * HEADS + h]);
    }
}

// ---------------- K_A: MLP (bias written LINEARLY at e) + 8B-record partition ----------------
// Bias never enters the sort: bias_by_e[e] is a coalesced 16B store.
// Only {e, jl<<24|i} (8B) goes through LDS staging -> bucket regions.
__global__ __launch_bounds__(512) void mlp_partition(
    const int* __restrict__ ei,
    const float* __restrict__ edge_attr,
    const h2* __restrict__ w1p, const float* __restrict__ be1,
    const h2* __restrict__ w2p, const float* __restrict__ be2,
    int* __restrict__ gcur,
    uint2* __restrict__ A_rec, uint4* __restrict__ bias_by_e)
{
    __shared__ int cnt[NB];
    __shared__ int base[NB];
    __shared__ int lbase[NB];
    __shared__ int total_s;
    __shared__ uint2 srec[PART_E];          // 16 KB
    __shared__ unsigned char sbkt[PART_E];  // 2 KB
    const int tid = threadIdx.x;
    if (tid < NB) cnt[tid] = 0;
    __syncthreads();
    const int e0 = blockIdx.x * PART_E;
    #pragma unroll
    for (int k = 0; k < EPT; ++k) {
        const int e = e0 + k * PART_T + tid;
        if (e < N_EDGES) atomicAdd(&cnt[ei[N_EDGES + e] / NPB], 1);
    }
    __syncthreads();
    if (tid < NB) lbase[tid] = cnt[tid];
    __syncthreads();
    for (int o = 1; o < NB; o <<= 1) {
        int t = 0;
        if (tid < NB && tid >= o) t = lbase[tid - o];
        __syncthreads();
        if (tid < NB) lbase[tid] += t;
        __syncthreads();
    }
    if (tid < NB) {
        const int inc = lbase[tid];
        const int c = cnt[tid];
        base[tid] = (c > 0) ? atomicAdd(&gcur[tid], c) : 0;
        lbase[tid] = inc - c;          // exclusive
        if (tid == NB - 1) total_s = inc;
        cnt[tid] = 0;                   // reuse as local cursor
    }
    __syncthreads();
    for (int k = 0; k < EPT; ++k) {
        const int e = e0 + k * PART_T + tid;
        if (e >= N_EDGES) break;
        const int i = ei[e];
        const int j = ei[N_EDGES + e];
        const int b = j / NPB;
        const int jl = j - b * NPB;
        // ---- MLP: 32 -> 32 SiLU -> 8, f16 dot2, weights via scalar pipe ----
        float a[EDGE_DIM];
        const float4* ar = (const float4*)(edge_attr + (size_t)e * EDGE_DIM);
        #pragma unroll
        for (int q = 0; q < EDGE_DIM / 4; ++q) {
            float4 v = ar[q];
            a[q * 4 + 0] = v.x; a[q * 4 + 1] = v.y;
            a[q * 4 + 2] = v.z; a[q * 4 + 3] = v.w;
        }
        h2 a2[EDGE_DIM / 2];
        #pragma unroll
        for (int kk = 0; kk < EDGE_DIM / 2; ++kk)
            a2[kk] = __builtin_amdgcn_cvt_pkrtz(a[2 * kk], a[2 * kk + 1]);
        float sil[EDGE_DIM];
        #pragma unroll 8
        for (int c = 0; c < EDGE_DIM; ++c) {
            float s = be1[c];
            #pragma unroll
            for (int kk = 0; kk < EDGE_DIM / 2; ++kk)
                s = __builtin_amdgcn_fdot2(a2[kk], w1p[c * 16 + kk], s, false);
            sil[c] = __fdividef(s, 1.0f + __expf(-s));
        }
        h2 s2[EDGE_DIM / 2];
        #pragma unroll
        for (int cc = 0; cc < EDGE_DIM / 2; ++cc)
            s2[cc] = __builtin_amdgcn_cvt_pkrtz(sil[2 * cc], sil[2 * cc + 1]);
        float b0f = be2[0], b1f = be2[1], b2f = be2[2], b3f = be2[3];
        float b4f = be2[4], b5f = be2[5], b6f = be2[6], b7f = be2[7];
        #pragma unroll
        for (int cc = 0; cc < EDGE_DIM / 2; ++cc) {
            b0f = __builtin_amdgcn_fdot2(s2[cc], w2p[0 * 16 + cc], b0f, false);
            b1f = __builtin_amdgcn_fdot2(s2[cc], w2p[1 * 16 + cc], b1f, false);
            b2f = __builtin_amdgcn_fdot2(s2[cc], w2p[2 * 16 + cc], b2f, false);
            b3f = __builtin_amdgcn_fdot2(s2[cc], w2p[3 * 16 + cc], b3f, false);
            b4f = __builtin_amdgcn_fdot2(s2[cc], w2p[4 * 16 + cc], b4f, false);
            b5f = __builtin_amdgcn_fdot2(s2[cc], w2p[5 * 16 + cc], b5f, false);
            b6f = __builtin_amdgcn_fdot2(s2[cc], w2p[6 * 16 + cc], b6f, false);
            b7f = __builtin_amdgcn_fdot2(s2[cc], w2p[7 * 16 + cc], b7f, false);
        }
        uint4 br;
        br.x = f2bf(b0f) | (f2bf(b1f) << 16);
        br.y = f2bf(b2f) | (f2bf(b3f) << 16);
        br.z = f2bf(b4f) | (f2bf(b5f) << 16);
        br.w = f2bf(b6f) | (f2bf(b7f) << 16);
        bias_by_e[e] = br;  // coalesced 16B store at linear position
        const int s = lbase[b] + atomicAdd(&cnt[b], 1);
        srec[s] = make_uint2((unsigned)e, ((unsigned)jl << 24) | (unsigned)i);
        sbkt[s] = (unsigned char)b;
    }
    __syncthreads();
    // coalesced copy-out of 8B records to bucket regions
    const int total = total_s;
    for (int s = tid; s < total; s += PART_T) {
        const int b = sbkt[s];
        const int gp = base[b] + (s - lbase[b]);
        if (gp < ACAP) A_rec[(size_t)b * ACAP + gp] = srec[s];
    }
}

// ---------------- K_B: per-bucket CSR build: offs + {e,i} per sorted position ----------------
__global__ __launch_bounds__(512) void bucket_perm(
    const int* __restrict__ gcur,
    const uint2* __restrict__ A_rec,
    int* __restrict__ offs, uint2* __restrict__ es_sorted)
{
    __shared__ int sc[NB];
    __shared__ int ldeg[NPB];
    __shared__ int loff[NPB + 1];
    __shared__ int gbase_s;
    const int tid = threadIdx.x;
    const int b = blockIdx.x;
    if (tid < NB) sc[tid] = min(gcur[tid], ACAP);
    __syncthreads();
    for (int o = 1; o < NB; o <<= 1) {
        int t = 0;
        if (tid < NB && tid >= o) t = sc[tid - o];
        __syncthreads();
        if (tid < NB) sc[tid] += t;
        __syncthreads();
    }
    if (tid == 0) gbase_s = (b == 0) ? 0 : sc[b - 1];
    if (tid < NPB) ldeg[tid] = 0;
    __syncthreads();
    const int gbase = gbase_s;
    const int nb = min(gcur[b], ACAP);
    for (int r = tid; r < nb; r += 512)
        atomicAdd(&ldeg[A_rec[(size_t)b * ACAP + r].y >> 24], 1);
    __syncthreads();
    if (tid < 256) sc[tid] = (tid < NPB) ? ldeg[tid] : 0;
    __syncthreads();
    for (int o = 1; o < 256; o <<= 1) {
        int t = 0;
        if (tid < 256 && tid >= o) t = sc[tid - o];
        __syncthreads();
        if (tid < 256) sc[tid] += t;
        __syncthreads();
    }
    if (tid == 0) loff[0] = 0;
    if (tid < NPB) { loff[tid + 1] = sc[tid]; ldeg[tid] = 0; }  // ldeg -> cursor
    __syncthreads();
    const int jbase = b * NPB;
    if (tid < NPB && jbase + tid < N_NODES) offs[jbase + tid] = gbase + loff[tid];
    if (b == NB - 1 && tid == 0) offs[N_NODES] = gbase + nb;
    for (int r = tid; r < nb; r += 512) {
        const uint2 rec = A_rec[(size_t)b * ACAP + r];
        const int jl = (int)(rec.y >> 24);
        const int slot = loff[jl] + atomicAdd(&ldeg[jl], 1);
        es_sorted[(size_t)gbase + slot] = make_uint2(rec.x, rec.y & 0xFFFFFFu);
    }
}

// ---------------- K1: Q/K/V projections; K,V packed bf16 into one uint row ----------------
__global__ __launch_bounds__(256) void qkv_proj(
    const float* __restrict__ x,
    const float* __restrict__ WQ, const float* __restrict__ bQ,
    const float* __restrict__ WK, const float* __restrict__ bK,
    const float* __restrict__ WV, const float* __restrict__ bV,
    float* __restrict__ Q, unsigned int* __restrict__ KV)
{
    __shared__ float sWQ[DIM * DIM];
    __shared__ float sWK[DIM * DIM];
    __shared__ float sWV[DIM * DIM];
    for (int t = threadIdx.x; t < DIM * DIM; t += blockDim.x) {
        sWQ[t] = WQ[t]; sWK[t] = WK[t]; sWV[t] = WV[t];
    }
    __syncthreads();
    const int lane = threadIdx.x & 63;
    const int wave = threadIdx.x >> 6;
    const int n = blockIdx.x * 4 + wave;
    if (n >= N_NODES) return;
    float xl = x[(size_t)n * DIM + lane];
    float aq = bQ[lane], ak = bK[lane], av = bV[lane];
    #pragma unroll
    for (int k = 0; k < DIM; ++k) {
        float xv = __shfl(xl, k, 64);
        aq += xv * sWQ[k * DIM + lane];
        ak += xv * sWK[k * DIM + lane];
        av += xv * sWV[k * DIM + lane];
    }
    Q[(size_t)n * DIM + lane] = aq;
    KV[(size_t)n * DIM + lane] = f2bf(ak) | (f2bf(av) << 16);  // K lo, V hi
}

// ---------------- K3: per-node attention + fused output projection ----------------
// Streams es_sorted {e,i}; gathers KV by i (critical path) and the 16B bias
// record by e from the linear 26MB table (independent chain, L2/L3-hot).
__global__ __launch_bounds__(256) void node_attn_out(
    const int* __restrict__ off,
    const uint2* __restrict__ es_sorted,
    const unsigned short* __restrict__ bias_u16,
    const float* __restrict__ Q, const unsigned int* __restrict__ KV,
    const float* __restrict__ WO, const float* __restrict__ bO,
    float* __restrict__ out)
{
    __shared__ float sWO[DIM * DIM];
    for (int t = threadIdx.x; t < DIM * DIM; t += 256) sWO[t] = WO[t];
    __syncthreads();
    const int lane = threadIdx.x & 63;
    const int wave = threadIdx.x >> 6;
    const int j = blockIdx.x * 4 + wave;
    if (j >= N_NODES) return;
    const int beg = off[j], end = off[j + 1];
    const int h = lane >> 3;
    const float qv = Q[(size_t)j * DIM + lane];
    const float inv_sqrt_dk = 0.35355339059327373f;
    float num = 0.0f;
    float den = 1e-12f;
    int t = beg;
    for (; t + 3 < end; t += 4) {
        const uint2 r0 = es_sorted[t + 0];
        const uint2 r1 = es_sorted[t + 1];
        const uint2 r2 = es_sorted[t + 2];
        const uint2 r3 = es_sorted[t + 3];
        const unsigned int u0 = KV[(size_t)r0.y * DIM + lane];
        const unsigned int u1 = KV[(size_t)r1.y * DIM + lane];
        const unsigned int u2 = KV[(size_t)r2.y * DIM + lane];
        const unsigned int u3 = KV[(size_t)r3.y * DIM + lane];
        const float b0 = bf_lo((unsigned int)bias_u16[(size_t)r0.x * HEADS + h]);
        const float b1 = bf_lo((unsigned int)bias_u16[(size_t)r1.x * HEADS + h]);
        const float b2 = bf_lo((unsigned int)bias_u16[(size_t)r2.x * HEADS + h]);
        const float b3 = bf_lo((unsigned int)bias_u16[(size_t)r3.x * HEADS + h]);
        float d0 = qv * bf_lo(u0);
        float d1 = qv * bf_lo(u1);
        float d2 = qv * bf_lo(u2);
        float d3 = qv * bf_lo(u3);
        d0 += __shfl_xor(d0, 1, 64); d1 += __shfl_xor(d1, 1, 64);
        d2 += __shfl_xor(d2, 1, 64); d3 += __shfl_xor(d3, 1, 64);
        d0 += __shfl_xor(d0, 2, 64); d1 += __shfl_xor(d1, 2, 64);
        d2 += __shfl_xor(d2, 2, 64); d3 += __shfl_xor(d3, 2, 64);
        d0 += __shfl_xor(d0, 4, 64); d1 += __shfl_xor(d1, 4, 64);
        d2 += __shfl_xor(d2, 4, 64); d3 += __shfl_xor(d3, 4, 64);
        const float e0 = __expf(d0 * inv_sqrt_dk + b0);
        const float e1 = __expf(d1 * inv_sqrt_dk + b1);
        const float e2 = __expf(d2 * inv_sqrt_dk + b2);
        const float e3 = __expf(d3 * inv_sqrt_dk + b3);
        num += e0 * bf_hi(u0) + e1 * bf_hi(u1) + e2 * bf_hi(u2) + e3 * bf_hi(u3);
        den += e0 + e1 + e2 + e3;
    }
    for (; t < end; ++t) {
        const uint2 r0 = es_sorted[t];
        const unsigned int u0 = KV[(size_t)r0.y * DIM + lane];
        const float b0 = bf_lo((unsigned int)bias_u16[(size_t)r0.x * HEADS + h]);
        float d0 = qv * bf_lo(u0);
        d0 += __shfl_xor(d0, 1, 64);
        d0 += __shfl_xor(d0, 2, 64);
        d0 += __shfl_xor(d0, 4, 64);
        const float e0 = __expf(d0 * inv_sqrt_dk + b0);
        num += e0 * bf_hi(u0);
        den += e0;
    }
    const float av = num / den;
    float acc = bO[lane];
    #pragma unroll
    for (int k = 0; k < DIM; ++k) {
        acc += __shfl(av, k, 64) * sWO[k * DIM + lane];
    }
    out[(size_t)j * DIM + lane] = acc;
}

extern "C" void kernel_launch(void* const* d_in, const int* in_sizes, int n_in,
                              void* d_out, int out_size, void* d_ws, size_t ws_size,
                              hipStream_t stream) {
    const float* x    = (const float*)d_in[0];
    const int*   ei   = (const int*)d_in[1];
    const float* ea   = (const float*)d_in[2];
    const float* WQ   = (const float*)d_in[3];
    const float* bQ   = (const float*)d_in[4];
    const float* WK   = (const float*)d_in[5];
    const float* bK   = (const float*)d_in[6];
    const float* WV   = (const float*)d_in[7];
    const float* bV   = (const float*)d_in[8];
    const float* WO   = (const float*)d_in[9];
    const float* bO   = (const float*)d_in[10];
    const float* We1  = (const float*)d_in[11];
    const float* be1  = (const float*)d_in[12];
    const float* We2  = (const float*)d_in[13];
    const float* be2  = (const float*)d_in[14];
    float* out = (float*)d_out;

    char* ws = (char*)d_ws;
    size_t off_b = 0;
    auto alloc = [&](size_t bytes) {
        void* p = ws + off_b;
        off_b += (bytes + 255) & ~(size_t)255;
        return p;
    };
    float*        Q         = (float*)alloc((size_t)N_NODES * DIM * sizeof(float));
    unsigned int* KV        = (unsigned int*)alloc((size_t)N_NODES * DIM * sizeof(unsigned int));
    uint2*        A_rec     = (uint2*)alloc((size_t)NB * ACAP * sizeof(uint2));
    uint4*        bias_by_e = (uint4*)alloc((size_t)N_EDGES * sizeof(uint4));
    uint2*        es_sorted = (uint2*)alloc((size_t)N_EDGES * sizeof(uint2));
    int*          offs      = (int*)alloc((size_t)(N_NODES + 1) * sizeof(int));
    int*          gcur      = (int*)alloc((size_t)NB * sizeof(int));
    h2*           w1p       = (h2*)alloc(512 * sizeof(h2));
    h2*           w2p       = (h2*)alloc(128 * sizeof(h2));

    (void)hipMemsetAsync(gcur, 0, (size_t)NB * sizeof(int), stream);

    pack_weights<<<1, 1024, 0, stream>>>(We1, We2, w1p, w2p);
    mlp_partition<<<(N_EDGES + PART_E - 1) / PART_E, PART_T, 0, stream>>>(
        ei, ea, w1p, be1, w2p, be2, gcur, A_rec, bias_by_e);
    bucket_perm<<<NB, 512, 0, stream>>>(gcur, A_rec, offs, es_sorted);
    qkv_proj<<<(N_NODES + 3) / 4, 256, 0, stream>>>(x, WQ, bQ, WK, bK, WV, bV, Q, KV);
    node_attn_out<<<(N_NODES + 3) / 4, 256, 0, stream>>>(offs, es_sorted,
                                                         (const unsigned short*)bias_by_e,
                                                         Q, KV, WO, bO, out);
}

// Round 15
// 325.430 us; speedup vs baseline: 1.7064x; 1.0725x over previous
//
#include <hip/hip_runtime.h>
#include <math.h>

#define N_NODES 50000
#define N_EDGES 1600000
#define DIM 64
#define HEADS 8
#define EDGE_DIM 32

#define NB 256      // destination buckets
#define NPB 196     // nodes per bucket (196*256 = 50176 >= 50000)
#define ACAP 8192   // per-bucket capacity (mean 6250, sd ~79 -> 24 sigma)
#define PART_T 256
#define EPT 4
#define PART_E (PART_T * EPT)  // 1024 edges per partition block

#define QKV_BLKS 12500  // ceil(N_NODES/4)

typedef __fp16 h2 __attribute__((ext_vector_type(2)));

// ---- bf16 helpers (RNE round via bit trick; inputs are finite) ----
__device__ __forceinline__ unsigned int f2bf(float f) {
    union { float f; unsigned int u; } c; c.f = f;
    unsigned int u = c.u;
    return (u + 0x7FFFu + ((u >> 16) & 1u)) >> 16;
}
__device__ __forceinline__ float bf_lo(unsigned int u) { return __uint_as_float(u << 16); }
__device__ __forceinline__ float bf_hi(unsigned int u) { return __uint_as_float(u & 0xFFFF0000u); }

// ---------------- K_prep: pack MLP weights + zero bucket cursors ----------------
__global__ __launch_bounds__(1024) void pack_weights(
    const float* __restrict__ We1, const float* __restrict__ We2,
    h2* __restrict__ w1p, h2* __restrict__ w2p, int* __restrict__ gcur)
{
    const int t = threadIdx.x;
    if (t < 512) {
        const int c = t >> 4, kk = t & 15;
        w1p[t] = __builtin_amdgcn_cvt_pkrtz(We1[(2 * kk) * EDGE_DIM + c],
                                            We1[(2 * kk + 1) * EDGE_DIM + c]);
    } else if (t < 512 + 128) {
        const int u = t - 512;
        const int h = u >> 4, cc = u & 15;
        w2p[u] = __builtin_amdgcn_cvt_pkrtz(We2[(2 * cc) * HEADS + h],
                                            We2[(2 * cc + 1) * HEADS + h]);
    } else if (t >= 768 && t < 768 + NB) {
        gcur[t - 768] = 0;
    }
}

// ---------------- K_A: MLP (bias written LINEARLY at e) + 8B-record partition ----------------
// 256-thr blocks (4-wave barrier groups), ~12 KB LDS -> high blocks/CU.
__global__ __launch_bounds__(256) void mlp_partition(
    const int* __restrict__ ei,
    const float* __restrict__ edge_attr,
    const h2* __restrict__ w1p, const float* __restrict__ be1,
    const h2* __restrict__ w2p, const float* __restrict__ be2,
    int* __restrict__ gcur,
    uint2* __restrict__ A_rec, uint4* __restrict__ bias_by_e)
{
    __shared__ int cnt[NB];
    __shared__ int base[NB];
    __shared__ int lbase[NB];
    __shared__ int total_s;
    __shared__ uint2 srec[PART_E];          // 8 KB
    __shared__ unsigned char sbkt[PART_E];  // 1 KB
    const int tid = threadIdx.x;
    cnt[tid] = 0;
    __syncthreads();
    const int e0 = blockIdx.x * PART_E;
    #pragma unroll
    for (int k = 0; k < EPT; ++k) {
        const int e = e0 + k * PART_T + tid;
        if (e < N_EDGES) atomicAdd(&cnt[ei[N_EDGES + e] / NPB], 1);
    }
    __syncthreads();
    lbase[tid] = cnt[tid];
    __syncthreads();
    for (int o = 1; o < NB; o <<= 1) {
        int t = (tid >= o) ? lbase[tid - o] : 0;
        __syncthreads();
        lbase[tid] += t;
        __syncthreads();
    }
    {
        const int inc = lbase[tid];
        const int c = cnt[tid];
        base[tid] = (c > 0) ? atomicAdd(&gcur[tid], c) : 0;
        lbase[tid] = inc - c;          // exclusive
        if (tid == NB - 1) total_s = inc;
        cnt[tid] = 0;                   // reuse as local cursor
    }
    __syncthreads();
    for (int k = 0; k < EPT; ++k) {
        const int e = e0 + k * PART_T + tid;
        if (e >= N_EDGES) break;
        const int i = ei[e];
        const int j = ei[N_EDGES + e];
        const int b = j / NPB;
        const int jl = j - b * NPB;
        // ---- MLP: 32 -> 32 SiLU -> 8, f16 dot2, weights via scalar pipe ----
        float a[EDGE_DIM];
        const float4* ar = (const float4*)(edge_attr + (size_t)e * EDGE_DIM);
        #pragma unroll
        for (int q = 0; q < EDGE_DIM / 4; ++q) {
            float4 v = ar[q];
            a[q * 4 + 0] = v.x; a[q * 4 + 1] = v.y;
            a[q * 4 + 2] = v.z; a[q * 4 + 3] = v.w;
        }
        h2 a2[EDGE_DIM / 2];
        #pragma unroll
        for (int kk = 0; kk < EDGE_DIM / 2; ++kk)
            a2[kk] = __builtin_amdgcn_cvt_pkrtz(a[2 * kk], a[2 * kk + 1]);
        float sil[EDGE_DIM];
        #pragma unroll 8
        for (int c = 0; c < EDGE_DIM; ++c) {
            float s = be1[c];
            #pragma unroll
            for (int kk = 0; kk < EDGE_DIM / 2; ++kk)
                s = __builtin_amdgcn_fdot2(a2[kk], w1p[c * 16 + kk], s, false);
            sil[c] = __fdividef(s, 1.0f + __expf(-s));
        }
        h2 s2[EDGE_DIM / 2];
        #pragma unroll
        for (int cc = 0; cc < EDGE_DIM / 2; ++cc)
            s2[cc] = __builtin_amdgcn_cvt_pkrtz(sil[2 * cc], sil[2 * cc + 1]);
        float b0f = be2[0], b1f = be2[1], b2f = be2[2], b3f = be2[3];
        float b4f = be2[4], b5f = be2[5], b6f = be2[6], b7f = be2[7];
        #pragma unroll
        for (int cc = 0; cc < EDGE_DIM / 2; ++cc) {
            b0f = __builtin_amdgcn_fdot2(s2[cc], w2p[0 * 16 + cc], b0f, false);
            b1f = __builtin_amdgcn_fdot2(s2[cc], w2p[1 * 16 + cc], b1f, false);
            b2f = __builtin_amdgcn_fdot2(s2[cc], w2p[2 * 16 + cc], b2f, false);
            b3f = __builtin_amdgcn_fdot2(s2[cc], w2p[3 * 16 + cc], b3f, false);
            b4f = __builtin_amdgcn_fdot2(s2[cc], w2p[4 * 16 + cc], b4f, false);
            b5f = __builtin_amdgcn_fdot2(s2[cc], w2p[5 * 16 + cc], b5f, false);
            b6f = __builtin_amdgcn_fdot2(s2[cc], w2p[6 * 16 + cc], b6f, false);
            b7f = __builtin_amdgcn_fdot2(s2[cc], w2p[7 * 16 + cc], b7f, false);
        }
        uint4 br;
        br.x = f2bf(b0f) | (f2bf(b1f) << 16);
        br.y = f2bf(b2f) | (f2bf(b3f) << 16);
        br.z = f2bf(b4f) | (f2bf(b5f) << 16);
        br.w = f2bf(b6f) | (f2bf(b7f) << 16);
        bias_by_e[e] = br;  // coalesced 16B store at linear position
        const int s = lbase[b] + atomicAdd(&cnt[b], 1);
        srec[s] = make_uint2((unsigned)e, ((unsigned)jl << 24) | (unsigned)i);
        sbkt[s] = (unsigned char)b;
    }
    __syncthreads();
    const int total = total_s;
    for (int s = tid; s < total; s += PART_T) {
        const int b = sbkt[s];
        const int gp = base[b] + (s - lbase[b]);
        if (gp < ACAP) A_rec[(size_t)b * ACAP + gp] = srec[s];
    }
}

// ---------------- K_B: heterogeneous grid — perm (blocks 0..NB-1) + qkv (rest) ----------------
// perm runs at 1 block/CU; the 12500 qkv blocks fill the idle CUs/waves.
__global__ __launch_bounds__(256) void perm_qkv(
    const int* __restrict__ gcur, const uint2* __restrict__ A_rec,
    int* __restrict__ offs, uint2* __restrict__ es_sorted,
    const float* __restrict__ x,
    const float* __restrict__ WQ, const float* __restrict__ bQ,
    const float* __restrict__ WK, const float* __restrict__ bK,
    const float* __restrict__ WV, const float* __restrict__ bV,
    float* __restrict__ Q, unsigned int* __restrict__ KV)
{
    __shared__ __align__(16) char smem[3 * DIM * DIM * sizeof(float)];  // 48 KB
    const int tid = threadIdx.x;
    if (blockIdx.x < NB) {
        // ---- per-bucket CSR build: offs + {e,i} per sorted position ----
        int* sc   = (int*)smem;          // NB
        int* ldeg = sc + NB;             // NPB
        int* loff = ldeg + NPB;          // NPB+1
        int* gb   = loff + NPB + 1;      // 1
        const int b = blockIdx.x;
        sc[tid] = min(gcur[tid], ACAP);
        __syncthreads();
        for (int o = 1; o < NB; o <<= 1) {
            int t = (tid >= o) ? sc[tid - o] : 0;
            __syncthreads();
            sc[tid] += t;
            __syncthreads();
        }
        if (tid == 0) gb[0] = (b == 0) ? 0 : sc[b - 1];
        if (tid < NPB) ldeg[tid] = 0;
        __syncthreads();
        const int gbase = gb[0];
        const int nb = min(gcur[b], ACAP);
        for (int r = tid; r < nb; r += 256)
            atomicAdd(&ldeg[A_rec[(size_t)b * ACAP + r].y >> 24], 1);
        __syncthreads();
        sc[tid] = (tid < NPB) ? ldeg[tid] : 0;
        __syncthreads();
        for (int o = 1; o < 256; o <<= 1) {
            int t = (tid >= o) ? sc[tid - o] : 0;
            __syncthreads();
            sc[tid] += t;
            __syncthreads();
        }
        if (tid == 0) loff[0] = 0;
        if (tid < NPB) { loff[tid + 1] = sc[tid]; ldeg[tid] = 0; }  // ldeg -> cursor
        __syncthreads();
        const int jbase = b * NPB;
        if (tid < NPB && jbase + tid < N_NODES) offs[jbase + tid] = gbase + loff[tid];
        if (b == NB - 1 && tid == 0) offs[N_NODES] = gbase + nb;
        for (int r = tid; r < nb; r += 256) {
            const uint2 rec = A_rec[(size_t)b * ACAP + r];
            const int jl = (int)(rec.y >> 24);
            const int slot = loff[jl] + atomicAdd(&ldeg[jl], 1);
            es_sorted[(size_t)gbase + slot] = make_uint2(rec.x, rec.y & 0xFFFFFFu);
        }
    } else {
        // ---- Q/K/V projections; K,V packed bf16 into one uint row ----
        float* sWQ = (float*)smem;
        float* sWK = sWQ + DIM * DIM;
        float* sWV = sWK + DIM * DIM;
        for (int t = tid; t < DIM * DIM; t += 256) {
            sWQ[t] = WQ[t]; sWK[t] = WK[t]; sWV[t] = WV[t];
        }
        __syncthreads();
        const int lane = tid & 63;
        const int wave = tid >> 6;
        const int n = (blockIdx.x - NB) * 4 + wave;
        if (n >= N_NODES) return;
        float xl = x[(size_t)n * DIM + lane];
        float aq = bQ[lane], ak = bK[lane], av = bV[lane];
        #pragma unroll
        for (int k = 0; k < DIM; ++k) {
            float xv = __shfl(xl, k, 64);
            aq += xv * sWQ[k * DIM + lane];
            ak += xv * sWK[k * DIM + lane];
            av += xv * sWV[k * DIM + lane];
        }
        Q[(size_t)n * DIM + lane] = aq;
        KV[(size_t)n * DIM + lane] = f2bf(ak) | (f2bf(av) << 16);  // K lo, V hi
    }
}

// ---------------- K3: per-node attention + fused output projection (8-deep unroll) ----------------
__global__ __launch_bounds__(256) void node_attn_out(
    const int* __restrict__ off,
    const uint2* __restrict__ es_sorted,
    const unsigned short* __restrict__ bias_u16,
    const float* __restrict__ Q, const unsigned int* __restrict__ KV,
    const float* __restrict__ WO, const float* __restrict__ bO,
    float* __restrict__ out)
{
    __shared__ float sWO[DIM * DIM];
    for (int t = threadIdx.x; t < DIM * DIM; t += 256) sWO[t] = WO[t];
    __syncthreads();
    const int lane = threadIdx.x & 63;
    const int wave = threadIdx.x >> 6;
    const int j = blockIdx.x * 4 + wave;
    if (j >= N_NODES) return;
    const int beg = off[j], end = off[j + 1];
    const int h = lane >> 3;
    const float qv = Q[(size_t)j * DIM + lane];
    const float inv_sqrt_dk = 0.35355339059327373f;
    float num = 0.0f;
    float den = 1e-12f;
    int t = beg;
    for (; t + 7 < end; t += 8) {
        uint2 r[8];
        unsigned int u[8];
        float bb[8], d[8];
        #pragma unroll
        for (int q = 0; q < 8; ++q) r[q] = es_sorted[t + q];
        #pragma unroll
        for (int q = 0; q < 8; ++q) u[q] = KV[(size_t)r[q].y * DIM + lane];
        #pragma unroll
        for (int q = 0; q < 8; ++q)
            bb[q] = bf_lo((unsigned int)bias_u16[(size_t)r[q].x * HEADS + h]);
        #pragma unroll
        for (int q = 0; q < 8; ++q) d[q] = qv * bf_lo(u[q]);
        #pragma unroll
        for (int q = 0; q < 8; ++q) d[q] += __shfl_xor(d[q], 1, 64);
        #pragma unroll
        for (int q = 0; q < 8; ++q) d[q] += __shfl_xor(d[q], 2, 64);
        #pragma unroll
        for (int q = 0; q < 8; ++q) d[q] += __shfl_xor(d[q], 4, 64);
        #pragma unroll
        for (int q = 0; q < 8; ++q) {
            const float ev = __expf(d[q] * inv_sqrt_dk + bb[q]);
            num += ev * bf_hi(u[q]);
            den += ev;
        }
    }
    for (; t + 3 < end; t += 4) {
        uint2 r[4];
        unsigned int u[4];
        float bb[4], d[4];
        #pragma unroll
        for (int q = 0; q < 4; ++q) r[q] = es_sorted[t + q];
        #pragma unroll
        for (int q = 0; q < 4; ++q) u[q] = KV[(size_t)r[q].y * DIM + lane];
        #pragma unroll
        for (int q = 0; q < 4; ++q)
            bb[q] = bf_lo((unsigned int)bias_u16[(size_t)r[q].x * HEADS + h]);
        #pragma unroll
        for (int q = 0; q < 4; ++q) d[q] = qv * bf_lo(u[q]);
        #pragma unroll
        for (int q = 0; q < 4; ++q) d[q] += __shfl_xor(d[q], 1, 64);
        #pragma unroll
        for (int q = 0; q < 4; ++q) d[q] += __shfl_xor(d[q], 2, 64);
        #pragma unroll
        for (int q = 0; q < 4; ++q) d[q] += __shfl_xor(d[q], 4, 64);
        #pragma unroll
        for (int q = 0; q < 4; ++q) {
            const float ev = __expf(d[q] * inv_sqrt_dk + bb[q]);
            num += ev * bf_hi(u[q]);
            den += ev;
        }
    }
    for (; t < end; ++t) {
        const uint2 r0 = es_sorted[t];
        const unsigned int u0 = KV[(size_t)r0.y * DIM + lane];
        const float b0 = bf_lo((unsigned int)bias_u16[(size_t)r0.x * HEADS + h]);
        float d0 = qv * bf_lo(u0);
        d0 += __shfl_xor(d0, 1, 64);
        d0 += __shfl_xor(d0, 2, 64);
        d0 += __shfl_xor(d0, 4, 64);
        const float e0 = __expf(d0 * inv_sqrt_dk + b0);
        num += e0 * bf_hi(u0);
        den += e0;
    }
    const float av = num / den;
    float acc = bO[lane];
    #pragma unroll
    for (int k = 0; k < DIM; ++k) {
        acc += __shfl(av, k, 64) * sWO[k * DIM + lane];
    }
    out[(size_t)j * DIM + lane] = acc;
}

extern "C" void kernel_launch(void* const* d_in, const int* in_sizes, int n_in,
                              void* d_out, int out_size, void* d_ws, size_t ws_size,
                              hipStream_t stream) {
    const float* x    = (const float*)d_in[0];
    const int*   ei   = (const int*)d_in[1];
    const float* ea   = (const float*)d_in[2];
    const float* WQ   = (const float*)d_in[3];
    const float* bQ   = (const float*)d_in[4];
    const float* WK   = (const float*)d_in[5];
    const float* bK   = (const float*)d_in[6];
    const float* WV   = (const float*)d_in[7];
    const float* bV   = (const float*)d_in[8];
    const float* WO   = (const float*)d_in[9];
    const float* bO   = (const float*)d_in[10];
    const float* We1  = (const float*)d_in[11];
    const float* be1  = (const float*)d_in[12];
    const float* We2  = (const float*)d_in[13];
    const float* be2  = (const float*)d_in[14];
    float* out = (float*)d_out;

    char* ws = (char*)d_ws;
    size_t off_b = 0;
    auto alloc = [&](size_t bytes) {
        void* p = ws + off_b;
        off_b += (bytes + 255) & ~(size_t)255;
        return p;
    };
    float*        Q         = (float*)alloc((size_t)N_NODES * DIM * sizeof(float));
    unsigned int* KV        = (unsigned int*)alloc((size_t)N_NODES * DIM * sizeof(unsigned int));
    uint2*        A_rec     = (uint2*)alloc((size_t)NB * ACAP * sizeof(uint2));
    uint4*        bias_by_e = (uint4*)alloc((size_t)N_EDGES * sizeof(uint4));
    uint2*        es_sorted = (uint2*)alloc((size_t)N_EDGES * sizeof(uint2));
    int*          offs      = (int*)alloc((size_t)(N_NODES + 1) * sizeof(int));
    int*          gcur      = (int*)alloc((size_t)NB * sizeof(int));
    h2*           w1p       = (h2*)alloc(512 * sizeof(h2));
    h2*           w2p       = (h2*)alloc(128 * sizeof(h2));

    pack_weights<<<1, 1024, 0, stream>>>(We1, We2, w1p, w2p, gcur);
    mlp_partition<<<(N_EDGES + PART_E - 1) / PART_E, PART_T, 0, stream>>>(
        ei, ea, w1p, be1, w2p, be2, gcur, A_rec, bias_by_e);
    perm_qkv<<<NB + QKV_BLKS, 256, 0, stream>>>(gcur, A_rec, offs, es_sorted,
                                                x, WQ, bQ, WK, bK, WV, bV, Q, KV);
    node_attn_out<<<(N_NODES + 3) / 4, 256, 0, stream>>>(offs, es_sorted,
                                                         (const unsigned short*)bias_by_e,
                                                         Q, KV, WO, bO, out);
}